// Round 7
// baseline (1053.071 us; speedup 1.0000x reference)
//
#include <hip/hip_runtime.h>
#include <hip/hip_bf16.h>
#include <math.h>

#define Hdim 128
#define NCn  8000
#define NVn  16000
#define NE   60000
#define LITERS 10

typedef __attribute__((ext_vector_type(8))) short s8v;   // 8 x bf16 (4 VGPRs)
typedef __attribute__((ext_vector_type(4))) float f4v;   // MFMA acc

__device__ __forceinline__ float elu_f(float x) { return x > 0.0f ? x : (expf(x) - 1.0f); }
__device__ __forceinline__ float sigm_f(float x) { return 1.0f / (1.0f + expf(-x)); }
__device__ __forceinline__ unsigned short f2b(float x) {
    __hip_bfloat16 h = __float2bfloat16(x); return *(unsigned short*)&h;
}
__device__ __forceinline__ float b2f(unsigned short u) {
    __hip_bfloat16 h; *(unsigned short*)&h = u; return __bfloat162float(h);
}

// ---------------- init: h = LN(0.1*f*W_in + b_in), fp32 + bf16 mirror ----------------
__global__ void init_kernel(const float* __restrict__ cf, const float* __restrict__ vf,
                            const float* __restrict__ Wc, const float* __restrict__ bc,
                            const float* __restrict__ Wv, const float* __restrict__ bv,
                            const float* __restrict__ gc, const float* __restrict__ bcl,
                            const float* __restrict__ gv, const float* __restrict__ bvl,
                            float* __restrict__ hc, float* __restrict__ hv,
                            unsigned short* __restrict__ hcb, unsigned short* __restrict__ hvb) {
    int node = blockIdx.x;
    int lane = threadIdx.x;  // 64 threads, 2 elements each
    const float *Win, *bin, *g, *bl;
    float f;
    float* outp;
    unsigned short* outb;
    if (node < NCn) {
        f = cf[node]; Win = Wc; bin = bc; g = gc; bl = bcl;
        outp = hc + (size_t)node * Hdim; outb = hcb + (size_t)node * Hdim;
    } else {
        int n2 = node - NCn;
        f = vf[n2]; Win = Wv; bin = bv; g = gv; bl = bvl;
        outp = hv + (size_t)n2 * Hdim; outb = hvb + (size_t)n2 * Hdim;
    }
    f *= 0.1f;
    float x0 = f * Win[lane] + bin[lane];
    float x1 = f * Win[lane + 64] + bin[lane + 64];
    float s = x0 + x1;
    float sq = x0 * x0 + x1 * x1;
    #pragma unroll
    for (int off = 32; off > 0; off >>= 1) {
        s += __shfl_xor(s, off);
        sq += __shfl_xor(sq, off);
    }
    float m = s * (1.0f / 128.0f);
    float v = sq * (1.0f / 128.0f) - m * m;
    float inv = 1.0f / sqrtf(v + 1e-6f);
    float o0 = g[lane]      * (x0 - m) * inv + bl[lane];
    float o1 = g[lane + 64] * (x1 - m) * inv + bl[lane + 64];
    outp[lane] = o0; outp[lane + 64] = o1;
    outb[lane] = f2b(o0); outb[lane + 64] = f2b(o1);
}

// ---------------- weight prep: cast to bf16 in MFMA FRAGMENT ORDER ----------------
// elem for (frag f, ktile kt, lane, j) at ((kt*F + f)*64 + lane)*8 + j,
// sourcing W[k][n] with n = f*16 + (lane&15), k = kt*32 + (lane>>4)*8 + j.
__global__ void prep_weights(const float* __restrict__ Wmsg_c, const float* __restrict__ Wmsg_v,
                             const float* __restrict__ Wns_c,  const float* __restrict__ Wns_v,
                             const float* __restrict__ Wg_c, const float* __restrict__ Ug_c,
                             const float* __restrict__ Wg_v, const float* __restrict__ Ug_v,
                             unsigned short* __restrict__ Fmsg_c, unsigned short* __restrict__ Fmsg_v,
                             unsigned short* __restrict__ Fns_c,  unsigned short* __restrict__ Fns_v,
                             unsigned short* __restrict__ Fcat_c, unsigned short* __restrict__ Fuh_c,
                             unsigned short* __restrict__ Fcat_v, unsigned short* __restrict__ Fuh_v) {
    int idx = blockIdx.x * blockDim.x + threadIdx.x;
    const int S1 = 4 * 32768;              // msg_c, msg_v, ns_c, ns_v  (F=8, KT=8, ld=128)
    const int S2 = S1 + 2 * 98304;         // cat_c, cat_v              (F=24, KT=8, ld=384)
    const int S3 = S2 + 2 * 16384;         // uh_c, uh_v                (F=8, KT=4, col+256)
    if (idx < S1) {
        int seg = idx >> 15, t = idx & 32767;
        const float* W = (seg == 0) ? Wmsg_c : (seg == 1) ? Wmsg_v : (seg == 2) ? Wns_c : Wns_v;
        unsigned short* out = (seg == 0) ? Fmsg_c : (seg == 1) ? Fmsg_v : (seg == 2) ? Fns_c : Fns_v;
        int j = t & 7, lane = (t >> 3) & 63, t2 = t >> 9;
        int f = t2 & 7, kt = t2 >> 3;
        int n = f * 16 + (lane & 15), k = kt * 32 + (lane >> 4) * 8 + j;
        out[t] = f2b(W[(size_t)k * 128 + n]);
    } else if (idx < S2) {
        int q = idx - S1;
        int seg = q / 98304, t = q - seg * 98304;
        const float* Wg = seg ? Wg_v : Wg_c;
        const float* Ug = seg ? Ug_v : Ug_c;
        unsigned short* out = seg ? Fcat_v : Fcat_c;
        int j = t & 7, lane = (t >> 3) & 63, t2 = t >> 9;
        int f = t2 % 24, kt = t2 / 24;
        int n = f * 16 + (lane & 15), k = kt * 32 + (lane >> 4) * 8 + j;
        out[t] = f2b((k < 128) ? Ug[(size_t)k * 384 + n] : Wg[(size_t)(k - 128) * 384 + n]);
    } else if (idx < S3) {
        int q = idx - S2;
        int seg = q >> 14, t = q & 16383;
        const float* Ug = seg ? Ug_v : Ug_c;
        unsigned short* out = seg ? Fuh_v : Fuh_c;
        int j = t & 7, lane = (t >> 3) & 63, t2 = t >> 9;
        int f = t2 & 7, kt = t2 >> 3;
        int n = f * 16 + (lane & 15), k = kt * 32 + (lane >> 4) * 8 + j;
        out[t] = f2b(Ug[(size_t)k * 384 + 256 + n]);
    }
}

// ---------------- CSR build (once per call) ----------------
__global__ void zero_int_kernel(int* __restrict__ p, int n) {
    int i = blockIdx.x * blockDim.x + threadIdx.x;
    if (i < n) p[i] = 0;
}
__global__ void hist_kernel(const int* __restrict__ tgt_c, const int* __restrict__ tgt_v,
                            int* __restrict__ cnt_c, int* __restrict__ cnt_v) {
    int e = blockIdx.x * blockDim.x + threadIdx.x;
    if (e >= NE) return;
    atomicAdd(&cnt_c[tgt_c[e]], 1);
    atomicAdd(&cnt_v[tgt_v[e]], 1);
}
__launch_bounds__(1024)
__global__ void scan_kernel(const int* __restrict__ cnt, int* __restrict__ rowptr, int n) {
    __shared__ int part[1024];
    int t = threadIdx.x;
    int chunk = (n + 1023) >> 10;
    int base = t * chunk;
    int s = 0;
    for (int i = 0; i < chunk; i++) { int idx = base + i; if (idx < n) s += cnt[idx]; }
    part[t] = s;
    __syncthreads();
    for (int off = 1; off < 1024; off <<= 1) {
        int u = (t >= off) ? part[t - off] : 0;
        __syncthreads();
        part[t] += u;
        __syncthreads();
    }
    int run = part[t] - s;  // exclusive offset
    for (int i = 0; i < chunk; i++) {
        int idx = base + i;
        if (idx < n) { rowptr[idx] = run; run += cnt[idx]; }
    }
    if (t == 0) rowptr[n] = part[1023];
}
// slot_c[e] = CSR position of edge e among edges targeting tgt_c[e] (likewise slot_v)
__global__ void fill_kernel(const int* __restrict__ tgt_c, const int* __restrict__ tgt_v,
                            const int* __restrict__ rp_c, const int* __restrict__ rp_v,
                            int* __restrict__ fill_c, int* __restrict__ fill_v,
                            int* __restrict__ slot_c, int* __restrict__ slot_v) {
    int e = blockIdx.x * blockDim.x + threadIdx.x;
    if (e >= NE) return;
    int tc = tgt_c[e];
    slot_c[e] = rp_c[tc] + atomicAdd(&fill_c[tc], 1);
    int tv = tgt_v[e];
    slot_v[e] = rp_v[tv] + atomicAdd(&fill_v[tv], 1);
}

// ---------------- both edge GEMMs in one launch; fragment-order B; CSR-slot writes ----------------
__launch_bounds__(256)
__global__ void edge_gemm_dual(const unsigned short* __restrict__ hvb,
                               const unsigned short* __restrict__ hcb,
                               const int* __restrict__ v2c_src, const int* __restrict__ v2c_tgt,
                               const int* __restrict__ c2v_src, const int* __restrict__ c2v_tgt,
                               const int* __restrict__ slot_c, const int* __restrict__ slot_v,
                               const unsigned short* __restrict__ Fc,
                               const unsigned short* __restrict__ Fv,
                               const float* __restrict__ bc, const float* __restrict__ bv,
                               unsigned short* __restrict__ msg_vc,
                               unsigned short* __restrict__ msg_cv,
                               int gridE) {
    __shared__ unsigned short sA[64 * 264];   // full [64 row][256 k] tile, stride 264
    const int tid = threadIdx.x;
    const int d = (blockIdx.x >= gridE) ? 1 : 0;
    const int blockM = (d ? (blockIdx.x - gridE) : blockIdx.x) * 64;
    const unsigned short* A1 = d ? hcb : hvb;
    const unsigned short* A2 = d ? hvb : hcb;
    const int* idx1 = d ? c2v_src : v2c_src;
    const int* idx2 = d ? c2v_tgt : v2c_tgt;
    const int* slot = d ? slot_v : slot_c;
    const unsigned short* Wf = d ? Fv : Fc;
    const float* bias = d ? bv : bc;
    unsigned short* out = d ? msg_cv : msg_vc;

    const int lane = tid & 63, wave = tid >> 6;
    const int quad = lane >> 4, l16 = lane & 15;
    const int wm = (wave >> 1) * 32, wfb = (wave & 1) * 4;   // frag base for this wave's 64 cols
    const int r = tid >> 2, ch = tid & 3;
    int gmc = blockM + r; if (gmc >= NE) gmc = NE - 1;
    const int ia1 = idx1[gmc];
    const int ia2 = idx2[gmc];

    // stage full A tile: cols [0:128) from A1, [128:256) from A2
    #pragma unroll
    for (int j = 0; j < 4; j++) {
        int k = ch * 8 + j * 32;
        *(s8v*)&sA[r * 264 + k]       = *(const s8v*)&A1[(size_t)ia1 * Hdim + k];
        *(s8v*)&sA[r * 264 + 128 + k] = *(const s8v*)&A2[(size_t)ia2 * Hdim + k];
    }
    __syncthreads();

    f4v acc[2][4];
    #pragma unroll
    for (int mt = 0; mt < 2; mt++)
        #pragma unroll
        for (int nt = 0; nt < 4; nt++) acc[mt][nt] = (f4v){0.f, 0.f, 0.f, 0.f};

    #pragma unroll
    for (int kt = 0; kt < 8; kt++) {
        s8v a[2], b[4];
        #pragma unroll
        for (int mt = 0; mt < 2; mt++)
            a[mt] = *(const s8v*)&sA[(wm + mt * 16 + l16) * 264 + kt * 32 + quad * 8];
        #pragma unroll
        for (int nt = 0; nt < 4; nt++)
            b[nt] = *(const s8v*)&Wf[((size_t)(kt * 8 + wfb + nt) * 64 + lane) * 8];
        #pragma unroll
        for (int mt = 0; mt < 2; mt++)
            #pragma unroll
            for (int nt = 0; nt < 4; nt++)
                acc[mt][nt] = __builtin_amdgcn_mfma_f32_16x16x32_bf16(a[mt], b[nt], acc[mt][nt], 0, 0, 0);
    }

    #pragma unroll
    for (int mt = 0; mt < 2; mt++) {
        #pragma unroll
        for (int reg = 0; reg < 4; reg++) {
            int mg = blockM + wm + mt * 16 + quad * 4 + reg;
            if (mg >= NE) continue;
            int sl = slot[mg];
            #pragma unroll
            for (int nt = 0; nt < 4; nt++) {
                int nl = (wfb + nt) * 16 + l16;
                float v = elu_f(acc[mt][nt][reg] + bias[nl]);
                out[(size_t)sl * Hdim + nl] = f2b(v);
            }
        }
    }
}

// ---------------- streaming segment-sum: one wave per node ----------------
// agg[n][:] = bf16( fp32-sum over CSR rows rp[n]..rp[n+1] of msg ). lane covers 2 cols (u32).
__launch_bounds__(256)
__global__ void agg_dual(const unsigned short* __restrict__ msg_vc,
                         const unsigned short* __restrict__ msg_cv,
                         const int* __restrict__ rp_c, const int* __restrict__ rp_v,
                         unsigned short* __restrict__ agg_c, unsigned short* __restrict__ agg_v) {
    int w = blockIdx.x * 4 + (threadIdx.x >> 6);   // global wave id over c then v nodes
    int lane = threadIdx.x & 63;
    const unsigned short* msg;
    const int* rp;
    unsigned short* agg;
    int node;
    if (w < NCn) { msg = msg_vc; rp = rp_c; agg = agg_c; node = w; }
    else         { msg = msg_cv; rp = rp_v; agg = agg_v; node = w - NCn; }
    int b0 = rp[node], e0 = rp[node + 1];
    float s0 = 0.0f, s1 = 0.0f;
    for (int j = b0; j < e0; j++) {
        unsigned int u = *(const unsigned int*)&msg[(size_t)j * Hdim + lane * 2];
        s0 += b2f((unsigned short)(u & 0xffff));
        s1 += b2f((unsigned short)(u >> 16));
    }
    unsigned int o = (unsigned int)f2b(s0) | ((unsigned int)f2b(s1) << 16);
    *(unsigned int*)&agg[(size_t)node * Hdim + lane * 2] = o;
}

// ---------------- fused node update (both node types); fragment-order B; streaming agg ----------------
__launch_bounds__(256)
__global__ void node_update_dual(unsigned short* __restrict__ hcb, unsigned short* __restrict__ hvb,
                                 float* __restrict__ hc, float* __restrict__ hv,
                                 const unsigned short* __restrict__ agg_c,
                                 const unsigned short* __restrict__ agg_v,
                                 const unsigned short* __restrict__ Fns_c, const float* __restrict__ bns_c,
                                 const unsigned short* __restrict__ Fns_v, const float* __restrict__ bns_v,
                                 const unsigned short* __restrict__ Fcat_c, const unsigned short* __restrict__ Fuh_c,
                                 const unsigned short* __restrict__ Fcat_v, const unsigned short* __restrict__ Fuh_v,
                                 const float* __restrict__ bg_c, const float* __restrict__ bg_v,
                                 int gridC) {
    __shared__ unsigned short sA[64 * 264];   // [row][k] K=256, stride 264
    const int tid = threadIdx.x;
    const int isV = (blockIdx.x >= gridC) ? 1 : 0;
    const int blockM = (isV ? (blockIdx.x - gridC) : blockIdx.x) * 64;
    unsigned short* hb = isV ? hvb : hcb;
    float* h = isV ? hv : hc;
    const unsigned short* agg = isV ? agg_v : agg_c;
    const unsigned short* Fns = isV ? Fns_v : Fns_c;
    const float* bns = isV ? bns_v : bns_c;
    const unsigned short* Fcat = isV ? Fcat_v : Fcat_c;
    const unsigned short* Fuh = isV ? Fuh_v : Fuh_c;
    const float* bg = isV ? bg_v : bg_c;

    const int lane = tid & 63, wave = tid >> 6;
    const int quad = lane >> 4, l16 = lane & 15;
    const int wm16 = wave * 16;               // wave's 16-row strip (wave-local)
    const int r = tid >> 2, ch = tid & 3;
    const int node = blockM + r;

    // ---- stage [hb | agg] rows into sA (all streaming, coalesced) ----
    #pragma unroll
    for (int j = 0; j < 4; j++) {
        int k = ch * 8 + j * 32;
        *(s8v*)&sA[r * 264 + k]       = *(const s8v*)&hb[(size_t)node * Hdim + k];
        *(s8v*)&sA[r * 264 + 128 + k] = *(const s8v*)&agg[(size_t)node * Hdim + k];
    }
    __syncthreads();

    // ---- phase 1: upd = elu([hb|agg] @ Wns + bns) ----
    f4v accN[8];
    #pragma unroll
    for (int nt = 0; nt < 8; nt++) accN[nt] = (f4v){0.f, 0.f, 0.f, 0.f};
    #pragma unroll
    for (int kt = 0; kt < 8; kt++) {
        s8v a = *(const s8v*)&sA[(wm16 + l16) * 264 + kt * 32 + quad * 8];
        #pragma unroll
        for (int nt = 0; nt < 8; nt++) {
            s8v b = *(const s8v*)&Fns[((size_t)(kt * 8 + nt) * 64 + lane) * 8];
            accN[nt] = __builtin_amdgcn_mfma_f32_16x16x32_bf16(a, b, accN[nt], 0, 0, 0);
        }
    }
    // write upd into own wave's strip, cols [128:256)
    #pragma unroll
    for (int nt = 0; nt < 8; nt++) {
        #pragma unroll
        for (int reg = 0; reg < 4; reg++) {
            int row = wm16 + quad * 4 + reg;
            int col = nt * 16 + l16;
            float v = elu_f(accN[nt][reg] + bns[col]);
            sA[row * 264 + 128 + col] = f2b(v);
        }
    }
    __syncthreads();

    // ---- phase 2a: S = [hb | upd] @ Wcat (24 col-tiles) ----
    f4v accS[24];
    #pragma unroll
    for (int nt = 0; nt < 24; nt++) accS[nt] = (f4v){0.f, 0.f, 0.f, 0.f};
    #pragma unroll
    for (int kt = 0; kt < 8; kt++) {
        s8v a = *(const s8v*)&sA[(wm16 + l16) * 264 + kt * 32 + quad * 8];
        #pragma unroll
        for (int nt = 0; nt < 24; nt++) {
            s8v b = *(const s8v*)&Fcat[((size_t)(kt * 24 + nt) * 64 + lane) * 8];
            accS[nt] = __builtin_amdgcn_mfma_f32_16x16x32_bf16(a, b, accS[nt], 0, 0, 0);
        }
    }

    // ---- phase 2b: Hh = hb @ Uh (8 col-tiles, K=128) ----
    f4v accH[8];
    #pragma unroll
    for (int nt = 0; nt < 8; nt++) accH[nt] = (f4v){0.f, 0.f, 0.f, 0.f};
    #pragma unroll
    for (int kt = 0; kt < 4; kt++) {
        s8v a = *(const s8v*)&sA[(wm16 + l16) * 264 + kt * 32 + quad * 8];
        #pragma unroll
        for (int nt = 0; nt < 8; nt++) {
            s8v b = *(const s8v*)&Fuh[((size_t)(kt * 8 + nt) * 64 + lane) * 8];
            accH[nt] = __builtin_amdgcn_mfma_f32_16x16x32_bf16(a, b, accH[nt], 0, 0, 0);
        }
    }

    // ---- gates (reset_after; cols t, 128+t, 256+t share l16) ----
    #pragma unroll
    for (int j = 0; j < 8; j++) {
        int t = j * 16 + l16;
        float bz = bg[t]       + bg[384 + t];
        float br = bg[128 + t] + bg[512 + t];
        float b0h = bg[256 + t];
        float b1h = bg[640 + t];
        #pragma unroll
        for (int reg = 0; reg < 4; reg++) {
            int row = blockM + wm16 + quad * 4 + reg;
            float Sz = accS[j][reg]      + bz;
            float Sr = accS[8 + j][reg]  + br;
            float Sh = accS[16 + j][reg];
            float Hh = accH[j][reg];
            float z = sigm_f(Sz);
            float rr = sigm_f(Sr);
            float hh = tanhf((Sh - Hh + b0h) + rr * (Hh + b1h));
            float hold = h[(size_t)row * Hdim + t];
            float hn = z * hold + (1.0f - z) * hh;
            h[(size_t)row * Hdim + t] = hn;
            hb[(size_t)row * Hdim + t] = f2b(hn);
        }
    }
}

// ---------------- final: out[i] = dot(hv[i], Wf) + bf ----------------
__global__ void final_kernel(const float* __restrict__ hv, const float* __restrict__ Wf,
                             const float* __restrict__ bf, float* __restrict__ out) {
    int node = blockIdx.x * 4 + (threadIdx.x >> 6);
    int lane = threadIdx.x & 63;
    const float* row = hv + (size_t)node * Hdim;
    float s = row[lane] * Wf[lane] + row[lane + 64] * Wf[lane + 64];
    #pragma unroll
    for (int off = 32; off > 0; off >>= 1) s += __shfl_xor(s, off);
    if (lane == 0) out[node] = s + bf[0];
}

extern "C" void kernel_launch(void* const* d_in, const int* in_sizes, int n_in,
                              void* d_out, int out_size, void* d_ws, size_t ws_size,
                              hipStream_t stream) {
    const float* cf      = (const float*)d_in[0];
    const float* vf      = (const float*)d_in[1];
    const int*   c2v_src = (const int*)d_in[2];
    const int*   c2v_tgt = (const int*)d_in[3];
    const int*   v2c_src = (const int*)d_in[4];
    const int*   v2c_tgt = (const int*)d_in[5];
    const float* Wc_in   = (const float*)d_in[6];
    const float* bc_in   = (const float*)d_in[7];
    const float* Wv_in   = (const float*)d_in[8];
    const float* bv_in   = (const float*)d_in[9];
    const float* gc_ln   = (const float*)d_in[10];
    const float* bc_ln   = (const float*)d_in[11];
    const float* gv_ln   = (const float*)d_in[12];
    const float* bv_ln   = (const float*)d_in[13];
    const float* Wmsg_c  = (const float*)d_in[14];
    const float* bmsg_c  = (const float*)d_in[15];
    const float* Wmsg_v  = (const float*)d_in[16];
    const float* bmsg_v  = (const float*)d_in[17];
    const float* Wns_c   = (const float*)d_in[18];
    const float* bns_c   = (const float*)d_in[19];
    const float* Wns_v   = (const float*)d_in[20];
    const float* bns_v   = (const float*)d_in[21];
    const float* Wg_c    = (const float*)d_in[22];
    const float* Ug_c    = (const float*)d_in[23];
    const float* bg_c    = (const float*)d_in[24];
    const float* Wg_v    = (const float*)d_in[25];
    const float* Ug_v    = (const float*)d_in[26];
    const float* bg_v    = (const float*)d_in[27];
    const float* Wf      = (const float*)d_in[28];
    const float* bf      = (const float*)d_in[29];
    float* out = (float*)d_out;

    // ---- workspace carve (256B-aligned) ----
    char* p = (char*)d_ws;
    #define CARVE(name, type, count) type* name = (type*)p; p += (((size_t)(count) * sizeof(type)) + 255) & ~(size_t)255;
    CARVE(hc,     float, NCn * Hdim)
    CARVE(hv,     float, NVn * Hdim)
    CARVE(msg_vc, unsigned short, NE * Hdim)
    CARVE(msg_cv, unsigned short, NE * Hdim)
    CARVE(hc_b,   unsigned short, NCn * Hdim)
    CARVE(hv_b,   unsigned short, NVn * Hdim)
    CARVE(agg_c,  unsigned short, NCn * Hdim)
    CARVE(agg_v,  unsigned short, NVn * Hdim)
    CARVE(Fmsg_c, unsigned short, 32768)
    CARVE(Fmsg_v, unsigned short, 32768)
    CARVE(Fns_c,  unsigned short, 32768)
    CARVE(Fns_v,  unsigned short, 32768)
    CARVE(Fcat_c, unsigned short, 98304)
    CARVE(Fuh_c,  unsigned short, 16384)
    CARVE(Fcat_v, unsigned short, 98304)
    CARVE(Fuh_v,  unsigned short, 16384)
    CARVE(rp_c,  int, NCn + 8)
    CARVE(rp_v,  int, NVn + 8)
    CARVE(slot_c, int, NE)
    CARVE(slot_v, int, NE)
    CARVE(cnts,  int, 48000)
    #undef CARVE
    int* cnt_c  = cnts;
    int* cnt_v  = cnts + NCn;
    int* fill_c = cnts + NCn + NVn;
    int* fill_v = cnts + 2 * NCn + NVn;

    // ---- once-per-call prep (7 dispatches) ----
    prep_weights<<<(4 * 32768 + 2 * 98304 + 2 * 16384 + 255) / 256, 256, 0, stream>>>(
        Wmsg_c, Wmsg_v, Wns_c, Wns_v, Wg_c, Ug_c, Wg_v, Ug_v,
        Fmsg_c, Fmsg_v, Fns_c, Fns_v, Fcat_c, Fuh_c, Fcat_v, Fuh_v);
    zero_int_kernel<<<(48000 + 255) / 256, 256, 0, stream>>>(cnts, 48000);
    hist_kernel<<<(NE + 255) / 256, 256, 0, stream>>>(v2c_tgt, c2v_tgt, cnt_c, cnt_v);
    scan_kernel<<<1, 1024, 0, stream>>>(cnt_c, rp_c, NCn);
    scan_kernel<<<1, 1024, 0, stream>>>(cnt_v, rp_v, NVn);
    fill_kernel<<<(NE + 255) / 256, 256, 0, stream>>>(v2c_tgt, c2v_tgt, rp_c, rp_v,
                                                      fill_c, fill_v, slot_c, slot_v);
    init_kernel<<<NCn + NVn, 64, 0, stream>>>(cf, vf, Wc_in, bc_in, Wv_in, bv_in,
                                              gc_ln, bc_ln, gv_ln, bv_ln, hc, hv, hc_b, hv_b);

    const int gridE = (NE + 63) / 64;   // 938
    const int gridC = NCn / 64;         // 125
    const int gridV = NVn / 64;         // 250

    for (int it = 0; it < LITERS; it++) {
        edge_gemm_dual<<<2 * gridE, 256, 0, stream>>>(
            hv_b, hc_b, v2c_src, v2c_tgt, c2v_src, c2v_tgt, slot_c, slot_v,
            Fmsg_c, Fmsg_v, bmsg_c, bmsg_v, msg_vc, msg_cv, gridE);
        agg_dual<<<(NCn + NVn) / 4, 256, 0, stream>>>(
            msg_vc, msg_cv, rp_c, rp_v, agg_c, agg_v);
        node_update_dual<<<gridC + gridV, 256, 0, stream>>>(
            hc_b, hv_b, hc, hv, agg_c, agg_v,
            Fns_c, bns_c, Fns_v, bns_v,
            Fcat_c, Fuh_c, Fcat_v, Fuh_v, bg_c, bg_v, gridC);
    }

    final_kernel<<<NVn / 4, 256, 0, stream>>>(hv, Wf, bf, out);
}

// Round 8
// 913.764 us; speedup vs baseline: 1.1525x; 1.1525x over previous
//
#include <hip/hip_runtime.h>
#include <hip/hip_bf16.h>
#include <math.h>

#define Hdim 128
#define NCn  8000
#define NVn  16000
#define NE   60000
#define LITERS 10

typedef __attribute__((ext_vector_type(8))) short s8v;   // 8 x bf16 (4 VGPRs)
typedef __attribute__((ext_vector_type(4))) float f4v;   // MFMA acc

__device__ __forceinline__ float elu_f(float x) { return x > 0.0f ? x : (expf(x) - 1.0f); }
__device__ __forceinline__ float sigm_f(float x) { return 1.0f / (1.0f + expf(-x)); }
__device__ __forceinline__ unsigned short f2b(float x) {
    __hip_bfloat16 h = __float2bfloat16(x); return *(unsigned short*)&h;
}
__device__ __forceinline__ float b2f(unsigned short u) {
    __hip_bfloat16 h; *(unsigned short*)&h = u; return __bfloat162float(h);
}

// ---------------- init: h = LN(0.1*f*W_in + b_in), fp32 + bf16 mirror ----------------
__global__ void init_kernel(const float* __restrict__ cf, const float* __restrict__ vf,
                            const float* __restrict__ Wc, const float* __restrict__ bc,
                            const float* __restrict__ Wv, const float* __restrict__ bv,
                            const float* __restrict__ gc, const float* __restrict__ bcl,
                            const float* __restrict__ gv, const float* __restrict__ bvl,
                            float* __restrict__ hc, float* __restrict__ hv,
                            unsigned short* __restrict__ hcb, unsigned short* __restrict__ hvb) {
    int node = blockIdx.x;
    int lane = threadIdx.x;  // 64 threads, 2 elements each
    const float *Win, *bin, *g, *bl;
    float f;
    float* outp;
    unsigned short* outb;
    if (node < NCn) {
        f = cf[node]; Win = Wc; bin = bc; g = gc; bl = bcl;
        outp = hc + (size_t)node * Hdim; outb = hcb + (size_t)node * Hdim;
    } else {
        int n2 = node - NCn;
        f = vf[n2]; Win = Wv; bin = bv; g = gv; bl = bvl;
        outp = hv + (size_t)n2 * Hdim; outb = hvb + (size_t)n2 * Hdim;
    }
    f *= 0.1f;
    float x0 = f * Win[lane] + bin[lane];
    float x1 = f * Win[lane + 64] + bin[lane + 64];
    float s = x0 + x1;
    float sq = x0 * x0 + x1 * x1;
    #pragma unroll
    for (int off = 32; off > 0; off >>= 1) {
        s += __shfl_xor(s, off);
        sq += __shfl_xor(sq, off);
    }
    float m = s * (1.0f / 128.0f);
    float v = sq * (1.0f / 128.0f) - m * m;
    float inv = 1.0f / sqrtf(v + 1e-6f);
    float o0 = g[lane]      * (x0 - m) * inv + bl[lane];
    float o1 = g[lane + 64] * (x1 - m) * inv + bl[lane + 64];
    outp[lane] = o0; outp[lane + 64] = o1;
    outb[lane] = f2b(o0); outb[lane + 64] = f2b(o1);
}

// ---------------- weight prep: cast to bf16 in MFMA FRAGMENT ORDER ----------------
// elem for (frag f, ktile kt, lane, j) at ((kt*F + f)*64 + lane)*8 + j,
// sourcing W[k][n] with n = f*16 + (lane&15), k = kt*32 + (lane>>4)*8 + j.
__global__ void prep_weights(const float* __restrict__ Wmsg_c, const float* __restrict__ Wmsg_v,
                             const float* __restrict__ Wns_c,  const float* __restrict__ Wns_v,
                             const float* __restrict__ Wg_c, const float* __restrict__ Ug_c,
                             const float* __restrict__ Wg_v, const float* __restrict__ Ug_v,
                             unsigned short* __restrict__ Fmsg_c, unsigned short* __restrict__ Fmsg_v,
                             unsigned short* __restrict__ Fns_c,  unsigned short* __restrict__ Fns_v,
                             unsigned short* __restrict__ Fcat_c, unsigned short* __restrict__ Fuh_c,
                             unsigned short* __restrict__ Fcat_v, unsigned short* __restrict__ Fuh_v) {
    int idx = blockIdx.x * blockDim.x + threadIdx.x;
    const int S1 = 4 * 32768;              // msg_c, msg_v, ns_c, ns_v  (F=8, KT=8, ld=128)
    const int S2 = S1 + 2 * 98304;         // cat_c, cat_v              (F=24, KT=8, ld=384)
    const int S3 = S2 + 2 * 16384;         // uh_c, uh_v                (F=8, KT=4, col+256)
    if (idx < S1) {
        int seg = idx >> 15, t = idx & 32767;
        const float* W = (seg == 0) ? Wmsg_c : (seg == 1) ? Wmsg_v : (seg == 2) ? Wns_c : Wns_v;
        unsigned short* out = (seg == 0) ? Fmsg_c : (seg == 1) ? Fmsg_v : (seg == 2) ? Fns_c : Fns_v;
        int j = t & 7, lane = (t >> 3) & 63, t2 = t >> 9;
        int f = t2 & 7, kt = t2 >> 3;
        int n = f * 16 + (lane & 15), k = kt * 32 + (lane >> 4) * 8 + j;
        out[t] = f2b(W[(size_t)k * 128 + n]);
    } else if (idx < S2) {
        int q = idx - S1;
        int seg = q / 98304, t = q - seg * 98304;
        const float* Wg = seg ? Wg_v : Wg_c;
        const float* Ug = seg ? Ug_v : Ug_c;
        unsigned short* out = seg ? Fcat_v : Fcat_c;
        int j = t & 7, lane = (t >> 3) & 63, t2 = t >> 9;
        int f = t2 % 24, kt = t2 / 24;
        int n = f * 16 + (lane & 15), k = kt * 32 + (lane >> 4) * 8 + j;
        out[t] = f2b((k < 128) ? Ug[(size_t)k * 384 + n] : Wg[(size_t)(k - 128) * 384 + n]);
    } else if (idx < S3) {
        int q = idx - S2;
        int seg = q >> 14, t = q & 16383;
        const float* Ug = seg ? Ug_v : Ug_c;
        unsigned short* out = seg ? Fuh_v : Fuh_c;
        int j = t & 7, lane = (t >> 3) & 63, t2 = t >> 9;
        int f = t2 & 7, kt = t2 >> 3;
        int n = f * 16 + (lane & 15), k = kt * 32 + (lane >> 4) * 8 + j;
        out[t] = f2b(Ug[(size_t)k * 384 + 256 + n]);
    }
}

// ---------------- CSR build (once per call) ----------------
__global__ void zero_int_kernel(int* __restrict__ p, int n) {
    int i = blockIdx.x * blockDim.x + threadIdx.x;
    if (i < n) p[i] = 0;
}
__global__ void hist_kernel(const int* __restrict__ tgt_c, const int* __restrict__ tgt_v,
                            int* __restrict__ cnt_c, int* __restrict__ cnt_v) {
    int e = blockIdx.x * blockDim.x + threadIdx.x;
    if (e >= NE) return;
    atomicAdd(&cnt_c[tgt_c[e]], 1);
    atomicAdd(&cnt_v[tgt_v[e]], 1);
}
__launch_bounds__(1024)
__global__ void scan_kernel(const int* __restrict__ cnt, int* __restrict__ rowptr, int n) {
    __shared__ int part[1024];
    int t = threadIdx.x;
    int chunk = (n + 1023) >> 10;
    int base = t * chunk;
    int s = 0;
    for (int i = 0; i < chunk; i++) { int idx = base + i; if (idx < n) s += cnt[idx]; }
    part[t] = s;
    __syncthreads();
    for (int off = 1; off < 1024; off <<= 1) {
        int u = (t >= off) ? part[t - off] : 0;
        __syncthreads();
        part[t] += u;
        __syncthreads();
    }
    int run = part[t] - s;  // exclusive offset
    for (int i = 0; i < chunk; i++) {
        int idx = base + i;
        if (idx < n) { rowptr[idx] = run; run += cnt[idx]; }
    }
    if (t == 0) rowptr[n] = part[1023];
}
// slot_c[e] = CSR position of edge e among edges targeting tgt_c[e] (likewise slot_v)
__global__ void fill_kernel(const int* __restrict__ tgt_c, const int* __restrict__ tgt_v,
                            const int* __restrict__ rp_c, const int* __restrict__ rp_v,
                            int* __restrict__ fill_c, int* __restrict__ fill_v,
                            int* __restrict__ slot_c, int* __restrict__ slot_v) {
    int e = blockIdx.x * blockDim.x + threadIdx.x;
    if (e >= NE) return;
    int tc = tgt_c[e];
    slot_c[e] = rp_c[tc] + atomicAdd(&fill_c[tc], 1);
    int tv = tgt_v[e];
    slot_v[e] = rp_v[tv] + atomicAdd(&fill_v[tv], 1);
}

// ---------------- both edge GEMMs in one launch; fragment-order B; CSR-slot writes ----------------
__launch_bounds__(256)
__global__ void edge_gemm_dual(const unsigned short* __restrict__ hvb,
                               const unsigned short* __restrict__ hcb,
                               const int* __restrict__ v2c_src, const int* __restrict__ v2c_tgt,
                               const int* __restrict__ c2v_src, const int* __restrict__ c2v_tgt,
                               const int* __restrict__ slot_c, const int* __restrict__ slot_v,
                               const unsigned short* __restrict__ Fc,
                               const unsigned short* __restrict__ Fv,
                               const float* __restrict__ bc, const float* __restrict__ bv,
                               unsigned short* __restrict__ msg_vc,
                               unsigned short* __restrict__ msg_cv,
                               int gridE) {
    __shared__ unsigned short sA[64 * 264];   // full [64 row][256 k] tile, stride 264
    const int tid = threadIdx.x;
    const int d = (blockIdx.x >= gridE) ? 1 : 0;
    const int blockM = (d ? (blockIdx.x - gridE) : blockIdx.x) * 64;
    const unsigned short* A1 = d ? hcb : hvb;
    const unsigned short* A2 = d ? hvb : hcb;
    const int* idx1 = d ? c2v_src : v2c_src;
    const int* idx2 = d ? c2v_tgt : v2c_tgt;
    const int* slot = d ? slot_v : slot_c;
    const unsigned short* Wf = d ? Fv : Fc;
    const float* bias = d ? bv : bc;
    unsigned short* out = d ? msg_cv : msg_vc;

    const int lane = tid & 63, wave = tid >> 6;
    const int quad = lane >> 4, l16 = lane & 15;
    const int wm = (wave >> 1) * 32, wfb = (wave & 1) * 4;   // frag base for this wave's 64 cols
    const int r = tid >> 2, ch = tid & 3;
    int gmc = blockM + r; if (gmc >= NE) gmc = NE - 1;
    const int ia1 = idx1[gmc];
    const int ia2 = idx2[gmc];

    // stage full A tile: cols [0:128) from A1, [128:256) from A2
    #pragma unroll
    for (int j = 0; j < 4; j++) {
        int k = ch * 8 + j * 32;
        *(s8v*)&sA[r * 264 + k]       = *(const s8v*)&A1[(size_t)ia1 * Hdim + k];
        *(s8v*)&sA[r * 264 + 128 + k] = *(const s8v*)&A2[(size_t)ia2 * Hdim + k];
    }
    __syncthreads();

    f4v acc[2][4];
    #pragma unroll
    for (int mt = 0; mt < 2; mt++)
        #pragma unroll
        for (int nt = 0; nt < 4; nt++) acc[mt][nt] = (f4v){0.f, 0.f, 0.f, 0.f};

    #pragma unroll
    for (int kt = 0; kt < 8; kt++) {
        s8v a[2], b[4];
        #pragma unroll
        for (int mt = 0; mt < 2; mt++)
            a[mt] = *(const s8v*)&sA[(wm + mt * 16 + l16) * 264 + kt * 32 + quad * 8];
        #pragma unroll
        for (int nt = 0; nt < 4; nt++)
            b[nt] = *(const s8v*)&Wf[((size_t)(kt * 8 + wfb + nt) * 64 + lane) * 8];
        #pragma unroll
        for (int mt = 0; mt < 2; mt++)
            #pragma unroll
            for (int nt = 0; nt < 4; nt++)
                acc[mt][nt] = __builtin_amdgcn_mfma_f32_16x16x32_bf16(a[mt], b[nt], acc[mt][nt], 0, 0, 0);
    }

    #pragma unroll
    for (int mt = 0; mt < 2; mt++) {
        #pragma unroll
        for (int reg = 0; reg < 4; reg++) {
            int mg = blockM + wm + mt * 16 + quad * 4 + reg;
            if (mg >= NE) continue;
            int sl = slot[mg];
            #pragma unroll
            for (int nt = 0; nt < 4; nt++) {
                int nl = (wfb + nt) * 16 + l16;
                float v = elu_f(acc[mt][nt][reg] + bias[nl]);
                out[(size_t)sl * Hdim + nl] = f2b(v);
            }
        }
    }
}

// ---------------- fused node update: single-wave blocks, 16 rows each ----------------
// In-kernel CSR gather; j-grouped phase 2 keeps only 4 live accumulators (low VGPR).
// Grid: blocks [0,500) -> c nodes, [500,1500) -> v nodes.
__launch_bounds__(64)
__global__ void node_update_dual(unsigned short* __restrict__ hcb, unsigned short* __restrict__ hvb,
                                 float* __restrict__ hc, float* __restrict__ hv,
                                 const unsigned short* __restrict__ msg_vc,
                                 const unsigned short* __restrict__ msg_cv,
                                 const int* __restrict__ rp_c, const int* __restrict__ rp_v,
                                 const unsigned short* __restrict__ Fns_c, const float* __restrict__ bns_c,
                                 const unsigned short* __restrict__ Fns_v, const float* __restrict__ bns_v,
                                 const unsigned short* __restrict__ Fcat_c, const unsigned short* __restrict__ Fuh_c,
                                 const unsigned short* __restrict__ Fcat_v, const unsigned short* __restrict__ Fuh_v,
                                 const float* __restrict__ bg_c, const float* __restrict__ bg_v) {
    __shared__ unsigned short sA[16 * 264];   // [row][k] K=256, stride 264 (8.4 KB)
    const int w = blockIdx.x;
    const int isV = (w >= 500) ? 1 : 0;
    const int blockM = (isV ? (w - 500) : w) * 16;
    unsigned short* hb = isV ? hvb : hcb;
    float* h = isV ? hv : hc;
    const unsigned short* msg = isV ? msg_cv : msg_vc;
    const int* rp = isV ? rp_v : rp_c;
    const unsigned short* Fns = isV ? Fns_v : Fns_c;
    const float* bns = isV ? bns_v : bns_c;
    const unsigned short* Fcat = isV ? Fcat_v : Fcat_c;
    const unsigned short* Fuh = isV ? Fuh_v : Fuh_c;
    const float* bg = isV ? bg_v : bg_c;

    const int lane = threadIdx.x;
    const int quad = lane >> 4, l16 = lane & 15;
    const int r = lane >> 2, ch = lane & 3;   // 4 threads per row
    const int node = blockM + r;

    // ---- stage hb rows into sA[:, 0:128) ----
    #pragma unroll
    for (int j = 0; j < 4; j++) {
        int k = ch * 8 + j * 32;
        *(s8v*)&sA[r * 264 + k] = *(const s8v*)&hb[(size_t)node * Hdim + k];
    }
    // ---- streaming CSR gather-sum into sA[:, 128:256): thread sums cols [ch*32,+32) ----
    {
        float a32[32];
        #pragma unroll
        for (int i = 0; i < 32; i++) a32[i] = 0.0f;
        int b0 = rp[node], e0 = rp[node + 1];
        for (int j = b0; j < e0; j++) {
            const unsigned short* mr = msg + (size_t)j * Hdim + ch * 32;
            #pragma unroll
            for (int q = 0; q < 4; q++) {
                s8v v = *(const s8v*)&mr[q * 8];
                #pragma unroll
                for (int x = 0; x < 8; x++) a32[q * 8 + x] += b2f((unsigned short)v[x]);
            }
        }
        #pragma unroll
        for (int q = 0; q < 4; q++) {
            s8v wv;
            #pragma unroll
            for (int x = 0; x < 8; x++) wv[x] = (short)f2b(a32[q * 8 + x]);
            *(s8v*)&sA[r * 264 + 128 + ch * 32 + q * 8] = wv;
        }
    }
    __syncthreads();   // single wave: compiles to a cheap waitcnt fence

    // ---- phase 1: upd = elu([hb|agg] @ Wns + bns) ----
    f4v accN[8];
    #pragma unroll
    for (int nt = 0; nt < 8; nt++) accN[nt] = (f4v){0.f, 0.f, 0.f, 0.f};
    #pragma unroll
    for (int kt = 0; kt < 8; kt++) {
        s8v a = *(const s8v*)&sA[l16 * 264 + kt * 32 + quad * 8];
        s8v b[8];
        #pragma unroll
        for (int nt = 0; nt < 8; nt++)
            b[nt] = *(const s8v*)&Fns[((size_t)(kt * 8 + nt) * 64 + lane) * 8];
        #pragma unroll
        for (int nt = 0; nt < 8; nt++)
            accN[nt] = __builtin_amdgcn_mfma_f32_16x16x32_bf16(a, b[nt], accN[nt], 0, 0, 0);
    }
    #pragma unroll
    for (int nt = 0; nt < 8; nt++) {
        #pragma unroll
        for (int reg = 0; reg < 4; reg++) {
            int row = quad * 4 + reg;
            int col = nt * 16 + l16;
            float v = elu_f(accN[nt][reg] + bns[col]);
            sA[row * 264 + 128 + col] = f2b(v);
        }
    }
    __syncthreads();

    // ---- phase 2, j-grouped: S_j, S_{8+j}, S_{16+j} (K=256) + Hh_j (K=128), then gates ----
    #pragma unroll
    for (int j = 0; j < 8; j++) {
        f4v sZ = (f4v){0.f, 0.f, 0.f, 0.f};
        f4v sR = (f4v){0.f, 0.f, 0.f, 0.f};
        f4v sH = (f4v){0.f, 0.f, 0.f, 0.f};
        f4v hH = (f4v){0.f, 0.f, 0.f, 0.f};
        #pragma unroll
        for (int kt = 0; kt < 8; kt++) {
            s8v a = *(const s8v*)&sA[l16 * 264 + kt * 32 + quad * 8];
            s8v bz = *(const s8v*)&Fcat[((size_t)(kt * 24 + j) * 64 + lane) * 8];
            s8v br = *(const s8v*)&Fcat[((size_t)(kt * 24 + 8 + j) * 64 + lane) * 8];
            s8v bh = *(const s8v*)&Fcat[((size_t)(kt * 24 + 16 + j) * 64 + lane) * 8];
            s8v bu;
            if (kt < 4) bu = *(const s8v*)&Fuh[((size_t)(kt * 8 + j) * 64 + lane) * 8];
            sZ = __builtin_amdgcn_mfma_f32_16x16x32_bf16(a, bz, sZ, 0, 0, 0);
            sR = __builtin_amdgcn_mfma_f32_16x16x32_bf16(a, br, sR, 0, 0, 0);
            sH = __builtin_amdgcn_mfma_f32_16x16x32_bf16(a, bh, sH, 0, 0, 0);
            if (kt < 4)
                hH = __builtin_amdgcn_mfma_f32_16x16x32_bf16(a, bu, hH, 0, 0, 0);
        }
        int t = j * 16 + l16;
        float bz2 = bg[t]       + bg[384 + t];
        float br2 = bg[128 + t] + bg[512 + t];
        float b0h = bg[256 + t];
        float b1h = bg[640 + t];
        #pragma unroll
        for (int reg = 0; reg < 4; reg++) {
            int row = blockM + quad * 4 + reg;
            float z = sigm_f(sZ[reg] + bz2);
            float rr = sigm_f(sR[reg] + br2);
            float hh = tanhf((sH[reg] - hH[reg] + b0h) + rr * (hH[reg] + b1h));
            float hold = h[(size_t)row * Hdim + t];
            float hn = z * hold + (1.0f - z) * hh;
            h[(size_t)row * Hdim + t] = hn;
            hb[(size_t)row * Hdim + t] = f2b(hn);
        }
    }
}

// ---------------- final: out[i] = dot(hv[i], Wf) + bf ----------------
__global__ void final_kernel(const float* __restrict__ hv, const float* __restrict__ Wf,
                             const float* __restrict__ bf, float* __restrict__ out) {
    int node = blockIdx.x * 4 + (threadIdx.x >> 6);
    int lane = threadIdx.x & 63;
    const float* row = hv + (size_t)node * Hdim;
    float s = row[lane] * Wf[lane] + row[lane + 64] * Wf[lane + 64];
    #pragma unroll
    for (int off = 32; off > 0; off >>= 1) s += __shfl_xor(s, off);
    if (lane == 0) out[node] = s + bf[0];
}

extern "C" void kernel_launch(void* const* d_in, const int* in_sizes, int n_in,
                              void* d_out, int out_size, void* d_ws, size_t ws_size,
                              hipStream_t stream) {
    const float* cf      = (const float*)d_in[0];
    const float* vf      = (const float*)d_in[1];
    const int*   c2v_src = (const int*)d_in[2];
    const int*   c2v_tgt = (const int*)d_in[3];
    const int*   v2c_src = (const int*)d_in[4];
    const int*   v2c_tgt = (const int*)d_in[5];
    const float* Wc_in   = (const float*)d_in[6];
    const float* bc_in   = (const float*)d_in[7];
    const float* Wv_in   = (const float*)d_in[8];
    const float* bv_in   = (const float*)d_in[9];
    const float* gc_ln   = (const float*)d_in[10];
    const float* bc_ln   = (const float*)d_in[11];
    const float* gv_ln   = (const float*)d_in[12];
    const float* bv_ln   = (const float*)d_in[13];
    const float* Wmsg_c  = (const float*)d_in[14];
    const float* bmsg_c  = (const float*)d_in[15];
    const float* Wmsg_v  = (const float*)d_in[16];
    const float* bmsg_v  = (const float*)d_in[17];
    const float* Wns_c   = (const float*)d_in[18];
    const float* bns_c   = (const float*)d_in[19];
    const float* Wns_v   = (const float*)d_in[20];
    const float* bns_v   = (const float*)d_in[21];
    const float* Wg_c    = (const float*)d_in[22];
    const float* Ug_c    = (const float*)d_in[23];
    const float* bg_c    = (const float*)d_in[24];
    const float* Wg_v    = (const float*)d_in[25];
    const float* Ug_v    = (const float*)d_in[26];
    const float* bg_v    = (const float*)d_in[27];
    const float* Wf      = (const float*)d_in[28];
    const float* bf      = (const float*)d_in[29];
    float* out = (float*)d_out;

    // ---- workspace carve (256B-aligned) ----
    char* p = (char*)d_ws;
    #define CARVE(name, type, count) type* name = (type*)p; p += (((size_t)(count) * sizeof(type)) + 255) & ~(size_t)255;
    CARVE(hc,     float, NCn * Hdim)
    CARVE(hv,     float, NVn * Hdim)
    CARVE(msg_vc, unsigned short, NE * Hdim)
    CARVE(msg_cv, unsigned short, NE * Hdim)
    CARVE(hc_b,   unsigned short, NCn * Hdim)
    CARVE(hv_b,   unsigned short, NVn * Hdim)
    CARVE(Fmsg_c, unsigned short, 32768)
    CARVE(Fmsg_v, unsigned short, 32768)
    CARVE(Fns_c,  unsigned short, 32768)
    CARVE(Fns_v,  unsigned short, 32768)
    CARVE(Fcat_c, unsigned short, 98304)
    CARVE(Fuh_c,  unsigned short, 16384)
    CARVE(Fcat_v, unsigned short, 98304)
    CARVE(Fuh_v,  unsigned short, 16384)
    CARVE(rp_c,  int, NCn + 8)
    CARVE(rp_v,  int, NVn + 8)
    CARVE(slot_c, int, NE)
    CARVE(slot_v, int, NE)
    CARVE(cnts,  int, 48000)
    #undef CARVE
    int* cnt_c  = cnts;
    int* cnt_v  = cnts + NCn;
    int* fill_c = cnts + NCn + NVn;
    int* fill_v = cnts + 2 * NCn + NVn;

    // ---- once-per-call prep (7 dispatches) ----
    prep_weights<<<(4 * 32768 + 2 * 98304 + 2 * 16384 + 255) / 256, 256, 0, stream>>>(
        Wmsg_c, Wmsg_v, Wns_c, Wns_v, Wg_c, Ug_c, Wg_v, Ug_v,
        Fmsg_c, Fmsg_v, Fns_c, Fns_v, Fcat_c, Fuh_c, Fcat_v, Fuh_v);
    zero_int_kernel<<<(48000 + 255) / 256, 256, 0, stream>>>(cnts, 48000);
    hist_kernel<<<(NE + 255) / 256, 256, 0, stream>>>(v2c_tgt, c2v_tgt, cnt_c, cnt_v);
    scan_kernel<<<1, 1024, 0, stream>>>(cnt_c, rp_c, NCn);
    scan_kernel<<<1, 1024, 0, stream>>>(cnt_v, rp_v, NVn);
    fill_kernel<<<(NE + 255) / 256, 256, 0, stream>>>(v2c_tgt, c2v_tgt, rp_c, rp_v,
                                                      fill_c, fill_v, slot_c, slot_v);
    init_kernel<<<NCn + NVn, 64, 0, stream>>>(cf, vf, Wc_in, bc_in, Wv_in, bv_in,
                                              gc_ln, bc_ln, gv_ln, bv_ln, hc, hv, hc_b, hv_b);

    const int gridE = (NE + 63) / 64;   // 938

    for (int it = 0; it < LITERS; it++) {
        edge_gemm_dual<<<2 * gridE, 256, 0, stream>>>(
            hv_b, hc_b, v2c_src, v2c_tgt, c2v_src, c2v_tgt, slot_c, slot_v,
            Fmsg_c, Fmsg_v, bmsg_c, bmsg_v, msg_vc, msg_cv, gridE);
        node_update_dual<<<1500, 64, 0, stream>>>(
            hc_b, hv_b, hc, hv, msg_vc, msg_cv,
            rp_c, rp_v,
            Fns_c, bns_c, Fns_v, bns_v,
            Fcat_c, Fuh_c, Fcat_v, Fuh_v, bg_c, bg_v);
    }

    final_kernel<<<NVn / 4, 256, 0, stream>>>(hv, Wf, bf, out);
}

// Round 9
// 755.377 us; speedup vs baseline: 1.3941x; 1.2097x over previous
//
#include <hip/hip_runtime.h>
#include <hip/hip_bf16.h>
#include <math.h>

#define Hdim 128
#define NCn  8000
#define NVn  16000
#define NE   60000
#define LITERS 10

typedef __attribute__((ext_vector_type(8))) short s8v;   // 8 x bf16 (4 VGPRs)
typedef __attribute__((ext_vector_type(4))) float f4v;   // MFMA acc

__device__ __forceinline__ float elu_f(float x) { return x > 0.0f ? x : (expf(x) - 1.0f); }
__device__ __forceinline__ float sigm_f(float x) { return 1.0f / (1.0f + expf(-x)); }
__device__ __forceinline__ unsigned short f2b(float x) {
    __hip_bfloat16 h = __float2bfloat16(x); return *(unsigned short*)&h;
}
__device__ __forceinline__ float b2f(unsigned short u) {
    __hip_bfloat16 h; *(unsigned short*)&h = u; return __bfloat162float(h);
}

// ---------------- init: h = LN(0.1*f*W_in + b_in), fp32 + bf16 mirror ----------------
__global__ void init_kernel(const float* __restrict__ cf, const float* __restrict__ vf,
                            const float* __restrict__ Wc, const float* __restrict__ bc,
                            const float* __restrict__ Wv, const float* __restrict__ bv,
                            const float* __restrict__ gc, const float* __restrict__ bcl,
                            const float* __restrict__ gv, const float* __restrict__ bvl,
                            float* __restrict__ hc, float* __restrict__ hv,
                            unsigned short* __restrict__ hcb, unsigned short* __restrict__ hvb) {
    int node = blockIdx.x;
    int lane = threadIdx.x;  // 64 threads, 2 elements each
    const float *Win, *bin, *g, *bl;
    float f;
    float* outp;
    unsigned short* outb;
    if (node < NCn) {
        f = cf[node]; Win = Wc; bin = bc; g = gc; bl = bcl;
        outp = hc + (size_t)node * Hdim; outb = hcb + (size_t)node * Hdim;
    } else {
        int n2 = node - NCn;
        f = vf[n2]; Win = Wv; bin = bv; g = gv; bl = bvl;
        outp = hv + (size_t)n2 * Hdim; outb = hvb + (size_t)n2 * Hdim;
    }
    f *= 0.1f;
    float x0 = f * Win[lane] + bin[lane];
    float x1 = f * Win[lane + 64] + bin[lane + 64];
    float s = x0 + x1;
    float sq = x0 * x0 + x1 * x1;
    #pragma unroll
    for (int off = 32; off > 0; off >>= 1) {
        s += __shfl_xor(s, off);
        sq += __shfl_xor(sq, off);
    }
    float m = s * (1.0f / 128.0f);
    float v = sq * (1.0f / 128.0f) - m * m;
    float inv = 1.0f / sqrtf(v + 1e-6f);
    float o0 = g[lane]      * (x0 - m) * inv + bl[lane];
    float o1 = g[lane + 64] * (x1 - m) * inv + bl[lane + 64];
    outp[lane] = o0; outp[lane + 64] = o1;
    outb[lane] = f2b(o0); outb[lane + 64] = f2b(o1);
}

// ---------------- weight prep: cast to bf16 in MFMA FRAGMENT ORDER ----------------
// elem for (frag f, ktile kt, lane, j) at ((kt*F + f)*64 + lane)*8 + j,
// sourcing W[k][n] with n = f*16 + (lane&15), k = kt*32 + (lane>>4)*8 + j.
__global__ void prep_weights(const float* __restrict__ Wmsg_c, const float* __restrict__ Wmsg_v,
                             const float* __restrict__ Wns_c,  const float* __restrict__ Wns_v,
                             const float* __restrict__ Wg_c, const float* __restrict__ Ug_c,
                             const float* __restrict__ Wg_v, const float* __restrict__ Ug_v,
                             unsigned short* __restrict__ Fmsg_c, unsigned short* __restrict__ Fmsg_v,
                             unsigned short* __restrict__ Fns_c,  unsigned short* __restrict__ Fns_v,
                             unsigned short* __restrict__ Fcat_c, unsigned short* __restrict__ Fuh_c,
                             unsigned short* __restrict__ Fcat_v, unsigned short* __restrict__ Fuh_v) {
    int idx = blockIdx.x * blockDim.x + threadIdx.x;
    const int S1 = 4 * 32768;              // msg_c, msg_v, ns_c, ns_v  (F=8, KT=8, ld=128)
    const int S2 = S1 + 2 * 98304;         // cat_c, cat_v              (F=24, KT=8, ld=384)
    const int S3 = S2 + 2 * 16384;         // uh_c, uh_v                (F=8, KT=4, col+256)
    if (idx < S1) {
        int seg = idx >> 15, t = idx & 32767;
        const float* W = (seg == 0) ? Wmsg_c : (seg == 1) ? Wmsg_v : (seg == 2) ? Wns_c : Wns_v;
        unsigned short* out = (seg == 0) ? Fmsg_c : (seg == 1) ? Fmsg_v : (seg == 2) ? Fns_c : Fns_v;
        int j = t & 7, lane = (t >> 3) & 63, t2 = t >> 9;
        int f = t2 & 7, kt = t2 >> 3;
        int n = f * 16 + (lane & 15), k = kt * 32 + (lane >> 4) * 8 + j;
        out[t] = f2b(W[(size_t)k * 128 + n]);
    } else if (idx < S2) {
        int q = idx - S1;
        int seg = q / 98304, t = q - seg * 98304;
        const float* Wg = seg ? Wg_v : Wg_c;
        const float* Ug = seg ? Ug_v : Ug_c;
        unsigned short* out = seg ? Fcat_v : Fcat_c;
        int j = t & 7, lane = (t >> 3) & 63, t2 = t >> 9;
        int f = t2 % 24, kt = t2 / 24;
        int n = f * 16 + (lane & 15), k = kt * 32 + (lane >> 4) * 8 + j;
        out[t] = f2b((k < 128) ? Ug[(size_t)k * 384 + n] : Wg[(size_t)(k - 128) * 384 + n]);
    } else if (idx < S3) {
        int q = idx - S2;
        int seg = q >> 14, t = q & 16383;
        const float* Ug = seg ? Ug_v : Ug_c;
        unsigned short* out = seg ? Fuh_v : Fuh_c;
        int j = t & 7, lane = (t >> 3) & 63, t2 = t >> 9;
        int f = t2 & 7, kt = t2 >> 3;
        int n = f * 16 + (lane & 15), k = kt * 32 + (lane >> 4) * 8 + j;
        out[t] = f2b(Ug[(size_t)k * 384 + 256 + n]);
    }
}

// ---------------- CSR build (once per call) ----------------
__global__ void zero_int_kernel(int* __restrict__ p, int n) {
    int i = blockIdx.x * blockDim.x + threadIdx.x;
    if (i < n) p[i] = 0;
}
__global__ void hist_kernel(const int* __restrict__ tgt_c, const int* __restrict__ tgt_v,
                            int* __restrict__ cnt_c, int* __restrict__ cnt_v) {
    int e = blockIdx.x * blockDim.x + threadIdx.x;
    if (e >= NE) return;
    atomicAdd(&cnt_c[tgt_c[e]], 1);
    atomicAdd(&cnt_v[tgt_v[e]], 1);
}
__launch_bounds__(1024)
__global__ void scan_kernel(const int* __restrict__ cnt, int* __restrict__ rowptr, int n) {
    __shared__ int part[1024];
    int t = threadIdx.x;
    int chunk = (n + 1023) >> 10;
    int base = t * chunk;
    int s = 0;
    for (int i = 0; i < chunk; i++) { int idx = base + i; if (idx < n) s += cnt[idx]; }
    part[t] = s;
    __syncthreads();
    for (int off = 1; off < 1024; off <<= 1) {
        int u = (t >= off) ? part[t - off] : 0;
        __syncthreads();
        part[t] += u;
        __syncthreads();
    }
    int run = part[t] - s;  // exclusive offset
    for (int i = 0; i < chunk; i++) {
        int idx = base + i;
        if (idx < n) { rowptr[idx] = run; run += cnt[idx]; }
    }
    if (t == 0) rowptr[n] = part[1023];
}
// slot_c[e] = CSR position of edge e among edges targeting tgt_c[e] (likewise slot_v)
__global__ void fill_kernel(const int* __restrict__ tgt_c, const int* __restrict__ tgt_v,
                            const int* __restrict__ rp_c, const int* __restrict__ rp_v,
                            int* __restrict__ fill_c, int* __restrict__ fill_v,
                            int* __restrict__ slot_c, int* __restrict__ slot_v) {
    int e = blockIdx.x * blockDim.x + threadIdx.x;
    if (e >= NE) return;
    int tc = tgt_c[e];
    slot_c[e] = rp_c[tc] + atomicAdd(&fill_c[tc], 1);
    int tv = tgt_v[e];
    slot_v[e] = rp_v[tv] + atomicAdd(&fill_v[tv], 1);
}

// ---------------- both edge GEMMs in one launch; fragment-order B; CSR-slot writes ----------------
__launch_bounds__(256)
__global__ void edge_gemm_dual(const unsigned short* __restrict__ hvb,
                               const unsigned short* __restrict__ hcb,
                               const int* __restrict__ v2c_src, const int* __restrict__ v2c_tgt,
                               const int* __restrict__ c2v_src, const int* __restrict__ c2v_tgt,
                               const int* __restrict__ slot_c, const int* __restrict__ slot_v,
                               const unsigned short* __restrict__ Fc,
                               const unsigned short* __restrict__ Fv,
                               const float* __restrict__ bc, const float* __restrict__ bv,
                               unsigned short* __restrict__ msg_vc,
                               unsigned short* __restrict__ msg_cv,
                               int gridE) {
    __shared__ unsigned short sA[64 * 264];   // full [64 row][256 k] tile, stride 264
    const int tid = threadIdx.x;
    const int d = (blockIdx.x >= gridE) ? 1 : 0;
    const int blockM = (d ? (blockIdx.x - gridE) : blockIdx.x) * 64;
    const unsigned short* A1 = d ? hcb : hvb;
    const unsigned short* A2 = d ? hvb : hcb;
    const int* idx1 = d ? c2v_src : v2c_src;
    const int* idx2 = d ? c2v_tgt : v2c_tgt;
    const int* slot = d ? slot_v : slot_c;
    const unsigned short* Wf = d ? Fv : Fc;
    const float* bias = d ? bv : bc;
    unsigned short* out = d ? msg_cv : msg_vc;

    const int lane = tid & 63, wave = tid >> 6;
    const int quad = lane >> 4, l16 = lane & 15;
    const int wm = (wave >> 1) * 32, wfb = (wave & 1) * 4;   // frag base for this wave's 64 cols
    const int r = tid >> 2, ch = tid & 3;
    int gmc = blockM + r; if (gmc >= NE) gmc = NE - 1;
    const int ia1 = idx1[gmc];
    const int ia2 = idx2[gmc];

    // stage full A tile: cols [0:128) from A1, [128:256) from A2
    #pragma unroll
    for (int j = 0; j < 4; j++) {
        int k = ch * 8 + j * 32;
        *(s8v*)&sA[r * 264 + k]       = *(const s8v*)&A1[(size_t)ia1 * Hdim + k];
        *(s8v*)&sA[r * 264 + 128 + k] = *(const s8v*)&A2[(size_t)ia2 * Hdim + k];
    }
    __syncthreads();

    f4v acc[2][4];
    #pragma unroll
    for (int mt = 0; mt < 2; mt++)
        #pragma unroll
        for (int nt = 0; nt < 4; nt++) acc[mt][nt] = (f4v){0.f, 0.f, 0.f, 0.f};

    #pragma unroll
    for (int kt = 0; kt < 8; kt++) {
        s8v a[2], b[4];
        #pragma unroll
        for (int mt = 0; mt < 2; mt++)
            a[mt] = *(const s8v*)&sA[(wm + mt * 16 + l16) * 264 + kt * 32 + quad * 8];
        #pragma unroll
        for (int nt = 0; nt < 4; nt++)
            b[nt] = *(const s8v*)&Wf[((size_t)(kt * 8 + wfb + nt) * 64 + lane) * 8];
        #pragma unroll
        for (int mt = 0; mt < 2; mt++)
            #pragma unroll
            for (int nt = 0; nt < 4; nt++)
                acc[mt][nt] = __builtin_amdgcn_mfma_f32_16x16x32_bf16(a[mt], b[nt], acc[mt][nt], 0, 0, 0);
    }

    #pragma unroll
    for (int mt = 0; mt < 2; mt++) {
        #pragma unroll
        for (int reg = 0; reg < 4; reg++) {
            int mg = blockM + wm + mt * 16 + quad * 4 + reg;
            if (mg >= NE) continue;
            int sl = slot[mg];
            #pragma unroll
            for (int nt = 0; nt < 4; nt++) {
                int nl = (wfb + nt) * 16 + l16;
                float v = elu_f(acc[mt][nt][reg] + bias[nl]);
                out[(size_t)sl * Hdim + nl] = f2b(v);
            }
        }
    }
}

// ---------------- fused node update: 16-row strip per block, 4 waves column-split ----------------
// Phase 1: wave w computes upd col-tiles {2w, 2w+1}. Phase 2: wave w handles gate
// col-groups j in {2w, 2w+1}. Per-wave B-load chain ~72 (vs 288 single-wave).
// Grid: blocks [0,500) -> c nodes, [500,1500) -> v nodes.
__launch_bounds__(256)
__global__ void node_update_dual(unsigned short* __restrict__ hcb, unsigned short* __restrict__ hvb,
                                 float* __restrict__ hc, float* __restrict__ hv,
                                 const unsigned short* __restrict__ msg_vc,
                                 const unsigned short* __restrict__ msg_cv,
                                 const int* __restrict__ rp_c, const int* __restrict__ rp_v,
                                 const unsigned short* __restrict__ Fns_c, const float* __restrict__ bns_c,
                                 const unsigned short* __restrict__ Fns_v, const float* __restrict__ bns_v,
                                 const unsigned short* __restrict__ Fcat_c, const unsigned short* __restrict__ Fuh_c,
                                 const unsigned short* __restrict__ Fcat_v, const unsigned short* __restrict__ Fuh_v,
                                 const float* __restrict__ bg_c, const float* __restrict__ bg_v) {
    __shared__ unsigned short sA[16 * 264];   // [row][k] K=256, stride 264 (8.4 KB)
    const int w = blockIdx.x;
    const int isV = (w >= 500) ? 1 : 0;
    const int blockM = (isV ? (w - 500) : w) * 16;
    unsigned short* hb = isV ? hvb : hcb;
    float* h = isV ? hv : hc;
    const unsigned short* msg = isV ? msg_cv : msg_vc;
    const int* rp = isV ? rp_v : rp_c;
    const unsigned short* Fns = isV ? Fns_v : Fns_c;
    const float* bns = isV ? bns_v : bns_c;
    const unsigned short* Fcat = isV ? Fcat_v : Fcat_c;
    const unsigned short* Fuh = isV ? Fuh_v : Fuh_c;
    const float* bg = isV ? bg_v : bg_c;

    const int tid = threadIdx.x;
    const int lane = tid & 63, wave = tid >> 6;
    const int quad = lane >> 4, l16 = lane & 15;
    const int r = tid >> 4, c8 = tid & 15;    // 16 threads per row, 8 cols (16B) each
    const int node = blockM + r;

    // ---- stage hb row chunk into sA[:, 0:128) ----
    *(s8v*)&sA[r * 264 + c8 * 8] = *(const s8v*)&hb[(size_t)node * Hdim + c8 * 8];
    // ---- streaming CSR gather-sum into sA[:, 128:256): thread sums cols [c8*8,+8) ----
    {
        float a8[8];
        #pragma unroll
        for (int i = 0; i < 8; i++) a8[i] = 0.0f;
        int b0 = rp[node], e0 = rp[node + 1];
        for (int j = b0; j < e0; j++) {
            s8v v = *(const s8v*)&msg[(size_t)j * Hdim + c8 * 8];
            #pragma unroll
            for (int x = 0; x < 8; x++) a8[x] += b2f((unsigned short)v[x]);
        }
        s8v wv;
        #pragma unroll
        for (int x = 0; x < 8; x++) wv[x] = (short)f2b(a8[x]);
        *(s8v*)&sA[r * 264 + 128 + c8 * 8] = wv;
    }
    __syncthreads();

    // ---- phase 1: wave computes upd col-tiles {2*wave, 2*wave+1} ----
    f4v accN[2];
    accN[0] = (f4v){0.f, 0.f, 0.f, 0.f};
    accN[1] = (f4v){0.f, 0.f, 0.f, 0.f};
    #pragma unroll
    for (int kt = 0; kt < 8; kt++) {
        s8v a = *(const s8v*)&sA[l16 * 264 + kt * 32 + quad * 8];
        s8v b0 = *(const s8v*)&Fns[((size_t)(kt * 8 + wave * 2 + 0) * 64 + lane) * 8];
        s8v b1 = *(const s8v*)&Fns[((size_t)(kt * 8 + wave * 2 + 1) * 64 + lane) * 8];
        accN[0] = __builtin_amdgcn_mfma_f32_16x16x32_bf16(a, b0, accN[0], 0, 0, 0);
        accN[1] = __builtin_amdgcn_mfma_f32_16x16x32_bf16(a, b1, accN[1], 0, 0, 0);
    }
    #pragma unroll
    for (int u = 0; u < 2; u++) {
        int col = (wave * 2 + u) * 16 + l16;
        #pragma unroll
        for (int reg = 0; reg < 4; reg++) {
            int row = quad * 4 + reg;
            float v = elu_f(accN[u][reg] + bns[col]);
            sA[row * 264 + 128 + col] = f2b(v);
        }
    }
    __syncthreads();

    // ---- phase 2: wave handles gate col-groups j = {2*wave, 2*wave+1} ----
    #pragma unroll
    for (int u = 0; u < 2; u++) {
        const int j = wave * 2 + u;
        f4v sZ = (f4v){0.f, 0.f, 0.f, 0.f};
        f4v sR = (f4v){0.f, 0.f, 0.f, 0.f};
        f4v sH = (f4v){0.f, 0.f, 0.f, 0.f};
        f4v hH = (f4v){0.f, 0.f, 0.f, 0.f};
        #pragma unroll
        for (int kt = 0; kt < 8; kt++) {
            s8v a = *(const s8v*)&sA[l16 * 264 + kt * 32 + quad * 8];
            s8v bz = *(const s8v*)&Fcat[((size_t)(kt * 24 + j) * 64 + lane) * 8];
            s8v br = *(const s8v*)&Fcat[((size_t)(kt * 24 + 8 + j) * 64 + lane) * 8];
            s8v bh = *(const s8v*)&Fcat[((size_t)(kt * 24 + 16 + j) * 64 + lane) * 8];
            s8v bu;
            if (kt < 4) bu = *(const s8v*)&Fuh[((size_t)(kt * 8 + j) * 64 + lane) * 8];
            sZ = __builtin_amdgcn_mfma_f32_16x16x32_bf16(a, bz, sZ, 0, 0, 0);
            sR = __builtin_amdgcn_mfma_f32_16x16x32_bf16(a, br, sR, 0, 0, 0);
            sH = __builtin_amdgcn_mfma_f32_16x16x32_bf16(a, bh, sH, 0, 0, 0);
            if (kt < 4)
                hH = __builtin_amdgcn_mfma_f32_16x16x32_bf16(a, bu, hH, 0, 0, 0);
        }
        int t = j * 16 + l16;
        float bz2 = bg[t]       + bg[384 + t];
        float br2 = bg[128 + t] + bg[512 + t];
        float b0h = bg[256 + t];
        float b1h = bg[640 + t];
        #pragma unroll
        for (int reg = 0; reg < 4; reg++) {
            int row = blockM + quad * 4 + reg;
            float z = sigm_f(sZ[reg] + bz2);
            float rr = sigm_f(sR[reg] + br2);
            float hh = tanhf((sH[reg] - hH[reg] + b0h) + rr * (hH[reg] + b1h));
            float hold = h[(size_t)row * Hdim + t];
            float hn = z * hold + (1.0f - z) * hh;
            h[(size_t)row * Hdim + t] = hn;
            hb[(size_t)row * Hdim + t] = f2b(hn);
        }
    }
}

// ---------------- final: out[i] = dot(hv[i], Wf) + bf ----------------
__global__ void final_kernel(const float* __restrict__ hv, const float* __restrict__ Wf,
                             const float* __restrict__ bf, float* __restrict__ out) {
    int node = blockIdx.x * 4 + (threadIdx.x >> 6);
    int lane = threadIdx.x & 63;
    const float* row = hv + (size_t)node * Hdim;
    float s = row[lane] * Wf[lane] + row[lane + 64] * Wf[lane + 64];
    #pragma unroll
    for (int off = 32; off > 0; off >>= 1) s += __shfl_xor(s, off);
    if (lane == 0) out[node] = s + bf[0];
}

extern "C" void kernel_launch(void* const* d_in, const int* in_sizes, int n_in,
                              void* d_out, int out_size, void* d_ws, size_t ws_size,
                              hipStream_t stream) {
    const float* cf      = (const float*)d_in[0];
    const float* vf      = (const float*)d_in[1];
    const int*   c2v_src = (const int*)d_in[2];
    const int*   c2v_tgt = (const int*)d_in[3];
    const int*   v2c_src = (const int*)d_in[4];
    const int*   v2c_tgt = (const int*)d_in[5];
    const float* Wc_in   = (const float*)d_in[6];
    const float* bc_in   = (const float*)d_in[7];
    const float* Wv_in   = (const float*)d_in[8];
    const float* bv_in   = (const float*)d_in[9];
    const float* gc_ln   = (const float*)d_in[10];
    const float* bc_ln   = (const float*)d_in[11];
    const float* gv_ln   = (const float*)d_in[12];
    const float* bv_ln   = (const float*)d_in[13];
    const float* Wmsg_c  = (const float*)d_in[14];
    const float* bmsg_c  = (const float*)d_in[15];
    const float* Wmsg_v  = (const float*)d_in[16];
    const float* bmsg_v  = (const float*)d_in[17];
    const float* Wns_c   = (const float*)d_in[18];
    const float* bns_c   = (const float*)d_in[19];
    const float* Wns_v   = (const float*)d_in[20];
    const float* bns_v   = (const float*)d_in[21];
    const float* Wg_c    = (const float*)d_in[22];
    const float* Ug_c    = (const float*)d_in[23];
    const float* bg_c    = (const float*)d_in[24];
    const float* Wg_v    = (const float*)d_in[25];
    const float* Ug_v    = (const float*)d_in[26];
    const float* bg_v    = (const float*)d_in[27];
    const float* Wf      = (const float*)d_in[28];
    const float* bf      = (const float*)d_in[29];
    float* out = (float*)d_out;

    // ---- workspace carve (256B-aligned) ----
    char* p = (char*)d_ws;
    #define CARVE(name, type, count) type* name = (type*)p; p += (((size_t)(count) * sizeof(type)) + 255) & ~(size_t)255;
    CARVE(hc,     float, NCn * Hdim)
    CARVE(hv,     float, NVn * Hdim)
    CARVE(msg_vc, unsigned short, NE * Hdim)
    CARVE(msg_cv, unsigned short, NE * Hdim)
    CARVE(hc_b,   unsigned short, NCn * Hdim)
    CARVE(hv_b,   unsigned short, NVn * Hdim)
    CARVE(Fmsg_c, unsigned short, 32768)
    CARVE(Fmsg_v, unsigned short, 32768)
    CARVE(Fns_c,  unsigned short, 32768)
    CARVE(Fns_v,  unsigned short, 32768)
    CARVE(Fcat_c, unsigned short, 98304)
    CARVE(Fuh_c,  unsigned short, 16384)
    CARVE(Fcat_v, unsigned short, 98304)
    CARVE(Fuh_v,  unsigned short, 16384)
    CARVE(rp_c,  int, NCn + 8)
    CARVE(rp_v,  int, NVn + 8)
    CARVE(slot_c, int, NE)
    CARVE(slot_v, int, NE)
    CARVE(cnts,  int, 48000)
    #undef CARVE
    int* cnt_c  = cnts;
    int* cnt_v  = cnts + NCn;
    int* fill_c = cnts + NCn + NVn;
    int* fill_v = cnts + 2 * NCn + NVn;

    // ---- once-per-call prep (7 dispatches) ----
    prep_weights<<<(4 * 32768 + 2 * 98304 + 2 * 16384 + 255) / 256, 256, 0, stream>>>(
        Wmsg_c, Wmsg_v, Wns_c, Wns_v, Wg_c, Ug_c, Wg_v, Ug_v,
        Fmsg_c, Fmsg_v, Fns_c, Fns_v, Fcat_c, Fuh_c, Fcat_v, Fuh_v);
    zero_int_kernel<<<(48000 + 255) / 256, 256, 0, stream>>>(cnts, 48000);
    hist_kernel<<<(NE + 255) / 256, 256, 0, stream>>>(v2c_tgt, c2v_tgt, cnt_c, cnt_v);
    scan_kernel<<<1, 1024, 0, stream>>>(cnt_c, rp_c, NCn);
    scan_kernel<<<1, 1024, 0, stream>>>(cnt_v, rp_v, NVn);
    fill_kernel<<<(NE + 255) / 256, 256, 0, stream>>>(v2c_tgt, c2v_tgt, rp_c, rp_v,
                                                      fill_c, fill_v, slot_c, slot_v);
    init_kernel<<<NCn + NVn, 64, 0, stream>>>(cf, vf, Wc_in, bc_in, Wv_in, bv_in,
                                              gc_ln, bc_ln, gv_ln, bv_ln, hc, hv, hc_b, hv_b);

    const int gridE = (NE + 63) / 64;   // 938

    for (int it = 0; it < LITERS; it++) {
        edge_gemm_dual<<<2 * gridE, 256, 0, stream>>>(
            hv_b, hc_b, v2c_src, v2c_tgt, c2v_src, c2v_tgt, slot_c, slot_v,
            Fmsg_c, Fmsg_v, bmsg_c, bmsg_v, msg_vc, msg_cv, gridE);
        node_update_dual<<<1500, 256, 0, stream>>>(
            hc_b, hv_b, hc, hv, msg_vc, msg_cv,
            rp_c, rp_v,
            Fns_c, bns_c, Fns_v, bns_v,
            Fcat_c, Fuh_c, Fcat_v, Fuh_v, bg_c, bg_v);
    }

    final_kernel<<<NVn / 4, 256, 0, stream>>>(hv, Wf, bf, out);
}